// Round 8
// baseline (748.815 us; speedup 1.0000x reference)
//
#include <hip/hip_runtime.h>

// Linear-chain CRF log-partition (backward DP), B=64, S=1024, T=128.
//
// r8: two fixes on top of r7's dead-beat exp-space recurrence (460us):
//  1) E = exp(transitions) is LAUNDERED through a one-time asm volatile
//     v_mov_b32 (opaque def: cannot be rematerialized) and consumed by raw
//     v_dot2_f32_f16 inline asm ("v" constraints). r7's VGPR_Count=40 proved
//     the compiler was re-loading trans + re-converting EVERY step (~300
//     VALU cyc/step) -- the flat ~1100-1500 cyc/step across r1-r7.
//  2) TWO chains per block (32 blocks x 4 waves): E is batch-independent,
//     so chains 2b,2b+1 share it. Both publish, cross ONE barrier, and issue
//     all 18 DS reads together -- write-drain+barrier+LDS-latency amortized
//     over 2 sequential DP steps, B's dots fill A's load shadow.
//
// Numerics (r7-proven): publish v' = q*u*e^{-GHAT} (f16); after barrier read
// z = q[0] of the consumed state (parity-double-buffered slot); q <- (E v')
// * rcp(z); Lam += GHAT + log z. Level L_k = g_k - GHAT: bounded, no
// feedback dynamics. log v' in [-12,+2]: inside f16 range.

typedef _Float16 h2 __attribute__((ext_vector_type(2)));

#define B_  64
#define S_  1024
#define T_  128
#define PAD_IDX 0
#define EOS_IDX 3
#define BOT_IDX 1
#define GHAT         5.35f
#define EXP_NEG_GHAT 0.004736892f   // e^{-5.35}

// raw dot: acc += dot(e_pair, p_pair); forces e in an arch VGPR at use
#define DOT(acc, e, p) \
  asm("v_dot2_f32_f16 %0, %1, %2, %0" : "+v"(acc) : "v"(e), "v"(p))

// add value from paired lane (lane^1) via DPP quad_perm [1,0,3,2]
static __device__ __forceinline__ float pair_sum(float x) {
  int p = __builtin_amdgcn_update_dpp(0, __builtin_bit_cast(int, x),
                                      0xB1, 0xF, 0xF, true);
  return x + __builtin_bit_cast(float, p);
}

__global__ __launch_bounds__(256, 1) void crf_logz_kernel(
    const int*   __restrict__ W,
    const float* __restrict__ emissions,
    const float* __restrict__ transitions,
    float*       __restrict__ out)
{
  const int blk  = blockIdx.x;            // handles chains 2*blk, 2*blk+1
  const int cA   = 2 * blk, cB = 2 * blk + 1;
  const int tid  = threadIdx.x;
  const int wv   = tid >> 6;
  const int l    = tid & 63;
  const int r    = (wv << 5) + (l >> 1);  // owned tag row 0..127
  const int half = l & 1;                 // column half

  __shared__ __align__(16) _Float16 vbufA[2][T_], vbufB[2][T_];
  __shared__ float zslotA[2], zslotB[2];
  __shared__ float fbufA[T_], fbufB[T_];

  // ---- E = exp(trans[r, half*64 .. +64)) as 32 packed f16 pairs,
  //      laundered through asm volatile: opaque def, NOT rematerializable.
  unsigned Eu[32];
  {
    const float2* tr = (const float2*)(transitions + (size_t)r * T_ + (half << 6));
    #pragma unroll
    for (int k = 0; k < 32; ++k) {
      float2 x = tr[k];
      h2 e; e.x = (_Float16)__expf(x.x); e.y = (_Float16)__expf(x.y);
      unsigned tmp = __builtin_bit_cast(unsigned, e);
      asm volatile("v_mov_b32 %0, %1" : "=v"(Eu[k]) : "v"(tmp));
    }
  }

  if (tid == 0) { zslotA[0] = zslotA[1] = 1.0f; zslotB[0] = zslotB[1] = 1.0f; }
  __syncthreads();   // once, outside the hot loop

  const int*   WrA = W + cA * S_;
  const int*   WrB = W + cB * S_;
  const float* emA = emissions + (size_t)cA * S_ * T_ + r;
  const float* emB = emissions + (size_t)cB * S_ * T_ + r;

  float qA = 1.0f, qB = 1.0f;      // exp-state; true Beta_r = log q + Lam
  float LamA = 0.0f, LamB = 0.0f;
  int   parA = 0, parB = 0;

  // 4-deep prefetch per chain: at iteration n, slot0 holds index n+1
  int   wA0 = WrA[S_-1], wA1 = WrA[S_-2], wA2 = WrA[S_-3], wA3 = WrA[S_-4];
  int   wB0 = WrB[S_-1], wB1 = WrB[S_-2], wB2 = WrB[S_-3], wB3 = WrB[S_-4];
  float eA0 = emA[(size_t)(S_-1)*T_], eA1 = emA[(size_t)(S_-2)*T_];
  float eA2 = emA[(size_t)(S_-3)*T_], eA3 = emA[(size_t)(S_-4)*T_];
  float eB0 = emB[(size_t)(S_-1)*T_], eB1 = emB[(size_t)(S_-2)*T_];
  float eB2 = emB[(size_t)(S_-3)*T_], eB3 = emB[(size_t)(S_-4)*T_];
  float usA0 = __expf(eA0) * EXP_NEG_GHAT, usA1 = __expf(eA1) * EXP_NEG_GHAT;
  float usB0 = __expf(eB0) * EXP_NEG_GHAT, usB1 = __expf(eB1) * EXP_NEG_GHAT;

  for (int n = S_ - 2; n >= 0; --n) {
    int pf = n - 3; if (pf < 0) pf = 0;            // clamped tail re-read: harmless
    int   wAn = WrA[pf],             wBn = WrB[pf];
    float eAn = emA[(size_t)pf*T_],  eBn = emB[(size_t)pf*T_];

    const bool aA = (wA0 != PAD_IDX) & (wA0 != EOS_IDX);   // block-uniform
    const bool aB = (wB0 != PAD_IDX) & (wB0 != EOS_IDX);

    if (aA & aB) {
      // ---------- fast path: both chains step (overwhelmingly common)
      vbufA[parA][r] = (_Float16)(qA * usA0);
      vbufB[parB][r] = (_Float16)(qB * usB0);
      asm volatile("s_waitcnt lgkmcnt(0)\n\ts_barrier" ::: "memory"); // no vmcnt drain

      float zA = zslotA[parA], zB = zslotB[parB];
      const uint4* vbA = ((const uint4*)&vbufA[parA][0]) + (half << 3);
      const uint4* vbB = ((const uint4*)&vbufB[parB][0]) + (half << 3);
      uint4 pA[8], pB[8];
      #pragma unroll
      for (int k = 0; k < 8; ++k) { pA[k] = vbA[k]; pB[k] = vbB[k]; }

      float xA0=0.f,xA1=0.f,xA2=0.f,xA3=0.f, xB0=0.f,xB1=0.f,xB2=0.f,xB3=0.f;
      #pragma unroll
      for (int k = 0; k < 8; ++k) {
        DOT(xA0, Eu[4*k+0], pA[k].x);  DOT(xB0, Eu[4*k+0], pB[k].x);
        DOT(xA1, Eu[4*k+1], pA[k].y);  DOT(xB1, Eu[4*k+1], pB[k].y);
        DOT(xA2, Eu[4*k+2], pA[k].z);  DOT(xB2, Eu[4*k+2], pB[k].z);
        DOT(xA3, Eu[4*k+3], pA[k].w);  DOT(xB3, Eu[4*k+3], pB[k].w);
      }
      float sA = pair_sum((xA0 + xA1) + (xA2 + xA3));
      float sB = pair_sum((xB0 + xB1) + (xB2 + xB3));

      qA = sA * __builtin_amdgcn_rcpf(zA);
      qB = sB * __builtin_amdgcn_rcpf(zB);
      if (tid == 0) { zslotA[parA ^ 1] = qA; zslotB[parB ^ 1] = qB; }
      LamA += GHAT + __logf(zA);
      LamB += GHAT + __logf(zB);
      parA ^= 1; parB ^= 1;
    } else if (aA | aB) {
      // ---------- rare path: exactly one chain steps
      if (aA) vbufA[parA][r] = (_Float16)(qA * usA0);
      if (aB) vbufB[parB][r] = (_Float16)(qB * usB0);
      asm volatile("s_waitcnt lgkmcnt(0)\n\ts_barrier" ::: "memory");
      if (aA) {
        float z = zslotA[parA];
        const uint4* vb = ((const uint4*)&vbufA[parA][0]) + (half << 3);
        float x0=0.f,x1=0.f,x2=0.f,x3=0.f;
        #pragma unroll
        for (int k = 0; k < 8; ++k) {
          uint4 pv = vb[k];
          DOT(x0, Eu[4*k+0], pv.x); DOT(x1, Eu[4*k+1], pv.y);
          DOT(x2, Eu[4*k+2], pv.z); DOT(x3, Eu[4*k+3], pv.w);
        }
        float s = pair_sum((x0 + x1) + (x2 + x3));
        qA = s * __builtin_amdgcn_rcpf(z);
        if (tid == 0) zslotA[parA ^ 1] = qA;
        LamA += GHAT + __logf(z);
        parA ^= 1;
      }
      if (aB) {
        float z = zslotB[parB];
        const uint4* vb = ((const uint4*)&vbufB[parB][0]) + (half << 3);
        float x0=0.f,x1=0.f,x2=0.f,x3=0.f;
        #pragma unroll
        for (int k = 0; k < 8; ++k) {
          uint4 pv = vb[k];
          DOT(x0, Eu[4*k+0], pv.x); DOT(x1, Eu[4*k+1], pv.y);
          DOT(x2, Eu[4*k+2], pv.z); DOT(x3, Eu[4*k+3], pv.w);
        }
        float s = pair_sum((x0 + x1) + (x2 + x3));
        qB = s * __builtin_amdgcn_rcpf(z);
        if (tid == 0) zslotB[parB ^ 1] = qB;
        LamB += GHAT + __logf(z);
        parB ^= 1;
      }
    }

    // shift prefetch pipelines
    wA0 = wA1; eA0 = eA1; usA0 = usA1;
    wA1 = wA2; eA1 = eA2;
    wA2 = wA3; eA2 = eA3;
    wA3 = wAn; eA3 = eAn;
    usA1 = __expf(eA1) * EXP_NEG_GHAT;
    wB0 = wB1; eB0 = eB1; usB0 = usB1;
    wB1 = wB2; eB1 = eB2;
    wB2 = wB3; eB2 = eB3;
    wB3 = wBn; eB3 = eBn;
    usB1 = __expf(eB1) * EXP_NEG_GHAT;
  }

  // ---- epilogue: f_r = trans[BOT,r] + em[.,0,r] + log q_r + Lam
  float tbot = transitions[BOT_IDX * T_ + r];
  fbufA[r] = tbot + eA0 + __logf(qA);   // eA0 ended as em[cA,0,r]
  fbufB[r] = tbot + eB0 + __logf(qB);
  __syncthreads();
  if (wv < 2) {
    const float* fb  = (wv == 0) ? fbufA : fbufB;
    float x0 = fb[l], x1 = fb[l + 64];
    float m = fmaxf(x0, x1);
    #pragma unroll
    for (int off = 32; off; off >>= 1) m = fmaxf(m, __shfl_xor(m, off));
    float s = __expf(x0 - m) + __expf(x1 - m);
    #pragma unroll
    for (int off = 32; off; off >>= 1) s += __shfl_xor(s, off);
    if (l == 0) out[(wv == 0) ? cA : cB] = ((wv == 0) ? LamA : LamB) + m + __logf(s);
  }
}

extern "C" void kernel_launch(void* const* d_in, const int* in_sizes, int n_in,
                              void* d_out, int out_size, void* d_ws, size_t ws_size,
                              hipStream_t stream) {
  const int*   W     = (const int*)d_in[0];
  const float* em    = (const float*)d_in[1];
  const float* trans = (const float*)d_in[2];
  float*       out   = (float*)d_out;
  (void)in_sizes; (void)n_in; (void)out_size; (void)d_ws; (void)ws_size;
  crf_logz_kernel<<<B_ / 2, 256, 0, stream>>>(W, em, trans, out);
}

// Round 9
// 491.631 us; speedup vs baseline: 1.5231x; 1.5231x over previous
//
#include <hip/hip_runtime.h>

// Linear-chain CRF log-partition (backward DP), B=64, S=1024, T=128.
//
// r9 = r7 (460us, absmax 0.0) + amdgpu_waves_per_eu(1,1).
//
// Root cause of r1-r8's flat VGPR_Count 40-52: the AMDGPU scheduler targets
// MAX occupancy (8 waves/EU -> ~64-VGPR budget) unless the max waves/EU is
// capped; __launch_bounds__'s 2nd arg only sets the MINIMUM. Under a 64-reg
// budget, E (32 regs) + working set (~40) doesn't fit, so E was either
// rematerialized each step (r1-r7: reload trans + re-exp, ~300 VALU
// cyc/step) or spilled to scratch (r8: asm-laundered defs can't remat ->
// buffer_load reloads, worse). amdgpu_waves_per_eu(1,1) sets the occupancy
// TARGET to 1 wave/EU -> 512-VGPR budget -> E stays resident. Our design is
// exactly 1 wave/EU anyway (64 blocks x 4 waves on 256 CUs): zero cost.
//
// Numerics (r7-proven, dead-beat normalizer):
//   publish   v' = q .* u .* e^{-GHAT}      (f16; NO z feedback at publish)
//   barrier;  z = q[0] of the consumed state (parity-double-buffered slot)
//   update    q <- (E v') * rcp(z);  Lam += GHAT + log z   (exact bookkeeping)
// Level L_k = log q_k[0] = g_k - GHAT: bounded +-1.5, no feedback dynamics.
// Published log v' in [-12.2, +1.7]: inside f16 range.
//
// Per active step: publish (1 mul + cvt + ds_write_b16); [lgkmcnt(0);
// s_barrier] (NO vmcnt drain -> 4-deep em prefetch stays in flight); 8x
// broadcast ds_read_b128; 32x v_dot2_f32_f16; DPP quad-perm pair-combine;
// rcp-scale. All off-path work (exp(em), log, Lam) hidden in the pipeline.

typedef _Float16 h2 __attribute__((ext_vector_type(2)));

#define B_  64
#define S_  1024
#define T_  128
#define PAD_IDX 0
#define EOS_IDX 3
#define BOT_IDX 1
#define GHAT         5.35f
#define EXP_NEG_GHAT 0.004736892f   // e^{-5.35}

#if defined(__has_builtin)
#if __has_builtin(__builtin_amdgcn_fdot2)
#define HAS_FDOT2 1
#endif
#endif

static __device__ __forceinline__ float dot2acc(unsigned eu, unsigned pu, float c) {
  h2 a = __builtin_bit_cast(h2, eu);
  h2 b = __builtin_bit_cast(h2, pu);
#ifdef HAS_FDOT2
  return __builtin_amdgcn_fdot2(a, b, c, false);
#else
  return fmaf((float)a.x, (float)b.x, fmaf((float)a.y, (float)b.y, c));
#endif
}

// add the value from the paired lane (lane ^ 1) via DPP quad_perm [1,0,3,2]
static __device__ __forceinline__ float pair_sum(float x) {
  int p = __builtin_amdgcn_update_dpp(0, __builtin_bit_cast(int, x),
                                      0xB1, 0xF, 0xF, true);
  return x + __builtin_bit_cast(float, p);
}

__global__ __launch_bounds__(256)
__attribute__((amdgpu_waves_per_eu(1, 1)))
void crf_logz_kernel(
    const int*   __restrict__ W,
    const float* __restrict__ emissions,
    const float* __restrict__ transitions,
    float*       __restrict__ out)
{
  const int b    = blockIdx.x;
  const int tid  = threadIdx.x;
  const int wv   = tid >> 6;
  const int l    = tid & 63;
  const int r    = (wv << 5) + (l >> 1);   // owned tag row 0..127
  const int half = l & 1;                  // column half: 0 -> [0,64), 1 -> [64,128)

  __shared__ __align__(16) _Float16 vbuf[2][T_];  // parity double-buffered v'
  __shared__ float zslot[2];                      // parity double-buffered q[0]
  __shared__ float fbuf[T_];

  // ---- E = exp(trans[r, half*64 .. +64)) as 32 packed f16 pairs (32 VGPRs)
  unsigned Eu[32];
  {
    const float2* tr = (const float2*)(transitions + (size_t)r * T_ + (half << 6));
    #pragma unroll
    for (int k = 0; k < 32; ++k) {
      float2 x = tr[k];
      h2 e; e.x = (_Float16)__expf(x.x); e.y = (_Float16)__expf(x.y);
      Eu[k] = __builtin_bit_cast(unsigned, e);
    }
  }

  if (tid == 0) { zslot[0] = 1.0f; zslot[1] = 1.0f; }
  __syncthreads();   // once, outside the hot loop

  const int*   Wrow = W + b * S_;
  const float* emb  = emissions + (size_t)b * S_ * T_ + r;  // stride T_ per step

  float q   = 1.0f;    // exp-state for row r; true Beta_r = log q + Lam
  float Lam = 0.0f;
  int   par = 0;

  // 4-deep prefetch: at iteration n, e0/w0 hold index n+1
  int   w0 = Wrow[S_ - 1], w1 = Wrow[S_ - 2], w2 = Wrow[S_ - 3], w3 = Wrow[S_ - 4];
  float e0 = emb[(size_t)(S_ - 1) * T_];
  float e1 = emb[(size_t)(S_ - 2) * T_];
  float e2 = emb[(size_t)(S_ - 3) * T_];
  float e3 = emb[(size_t)(S_ - 4) * T_];
  float us0 = __expf(e0) * EXP_NEG_GHAT;   // u * e^{-GHAT}, ready for publish
  float us1 = __expf(e1) * EXP_NEG_GHAT;

  for (int n = S_ - 2; n >= 0; --n) {
    // keep E alive in VGPRs at loop top -- zero instructions
    asm volatile("" :: "v"(Eu[0]),  "v"(Eu[1]),  "v"(Eu[2]),  "v"(Eu[3]),
                       "v"(Eu[4]),  "v"(Eu[5]),  "v"(Eu[6]),  "v"(Eu[7]),
                       "v"(Eu[8]),  "v"(Eu[9]),  "v"(Eu[10]), "v"(Eu[11]),
                       "v"(Eu[12]), "v"(Eu[13]), "v"(Eu[14]), "v"(Eu[15]));
    asm volatile("" :: "v"(Eu[16]), "v"(Eu[17]), "v"(Eu[18]), "v"(Eu[19]),
                       "v"(Eu[20]), "v"(Eu[21]), "v"(Eu[22]), "v"(Eu[23]),
                       "v"(Eu[24]), "v"(Eu[25]), "v"(Eu[26]), "v"(Eu[27]),
                       "v"(Eu[28]), "v"(Eu[29]), "v"(Eu[30]), "v"(Eu[31]));

    int pf = n - 3; if (pf < 0) pf = 0;            // clamped tail re-read: harmless
    int   wn = Wrow[pf];
    float en = emb[(size_t)pf * T_];

    if ((w0 != PAD_IDX) & (w0 != EOS_IDX)) {       // block-uniform branch
      // publish v' = q * u * e^{-GHAT}  (us0 precomputed off-path)
      float v = q * us0;
      vbuf[par][r] = (_Float16)v;                  // pair-lanes write same data
      // drain own DS writes, then barrier; NO vmcnt drain (prefetch in flight)
      asm volatile("s_waitcnt lgkmcnt(0)\n\ts_barrier" ::: "memory");

      float z = zslot[par];                        // q[0] of the state consumed NOW
      const uint4* vb = ((const uint4*)(&vbuf[par][0])) + (half << 3);
      float a0 = 0.f, a1 = 0.f, a2 = 0.f, a3 = 0.f;
      #pragma unroll
      for (int k = 0; k < 8; ++k) {
        uint4 pv = vb[k];                          // 2-way broadcast ds_read_b128
        a0 = dot2acc(Eu[4*k+0], pv.x, a0);
        a1 = dot2acc(Eu[4*k+1], pv.y, a1);
        a2 = dot2acc(Eu[4*k+2], pv.z, a2);
        a3 = dot2acc(Eu[4*k+3], pv.w, a3);
      }
      float s_half = (a0 + a1) + (a2 + a3);
      float s = pair_sum(s_half);                  // full row sum, both pair-lanes

      float rz = __builtin_amdgcn_rcpf(z);         // uniform across lanes
      q = s * rz;                                  // dead-beat: L_{k+1} = g_k - GHAT
      if (tid == 0) zslot[par ^ 1] = q;            // row 0's value for NEXT step
      Lam += GHAT + __logf(z);                     // exact compensation (off-path)
      par ^= 1;
    }
    // shift prefetch pipeline
    w0 = w1; e0 = e1; us0 = us1;
    w1 = w2; e1 = e2;
    w2 = w3; e2 = e3;
    w3 = wn; e3 = en;
    us1 = __expf(e1) * EXP_NEG_GHAT;               // e1 = index n, used at iter n-1
  }

  // ---- epilogue: f_r = trans[BOT,r] + em[b,0,r] + log q_r + Lam
  float f = transitions[BOT_IDX * T_ + r] + e0 + __logf(q);
  fbuf[r] = f;                                     // pair-lanes duplicate: benign
  __syncthreads();
  if (tid < 64) {
    float x0 = fbuf[tid], x1 = fbuf[tid + 64];
    float m = fmaxf(x0, x1);
    #pragma unroll
    for (int off = 32; off; off >>= 1) m = fmaxf(m, __shfl_xor(m, off));
    float s = __expf(x0 - m) + __expf(x1 - m);
    #pragma unroll
    for (int off = 32; off; off >>= 1) s += __shfl_xor(s, off);
    if (tid == 0) out[b] = Lam + m + __logf(s);
  }
}

extern "C" void kernel_launch(void* const* d_in, const int* in_sizes, int n_in,
                              void* d_out, int out_size, void* d_ws, size_t ws_size,
                              hipStream_t stream) {
  const int*   W     = (const int*)d_in[0];
  const float* em    = (const float*)d_in[1];
  const float* trans = (const float*)d_in[2];
  float*       out   = (float*)d_out;
  (void)in_sizes; (void)n_in; (void)out_size; (void)d_ws; (void)ws_size;
  crf_logz_kernel<<<B_, 256, 0, stream>>>(W, em, trans, out);
}

// Round 11
// 429.769 us; speedup vs baseline: 1.7424x; 1.1439x over previous
//
#include <hip/hip_runtime.h>

// Linear-chain CRF log-partition (backward DP), B=64, S=1024, T=128.
//
// r11 = r10 with the compile fix: __builtin_amdgcn_update_dpp requires an
// IMMEDIATE dpp-ctrl -> template parameter instead of runtime arg.
//
// Design (vs r9, 467us):
//  1) DS-pipe occupancy: r9 issued 32x ds_read_b128/step (~384 cyc @ ~12
//     cyc/inst). Now each QUAD of lanes owns 2 rows and splits the 128
//     columns 4 ways -> 64 B/lane -> 16x ds_read_b128/step total. Row sums
//     completed with two DPP quad_perm adds (xor1=0xB1, xor2=0x4E).
//     Per-lane dots halve to 32x v_dot2_f32_f16.
//  2) The per-step W load was block-uniform -> s_load -> lgkmcnt, so the
//     in-loop "s_waitcnt lgkmcnt(0)" drain stalled on SMEM every step. Now
//     W is consumed once per 64-step chunk: one VECTOR load of 64 ids +
//     __ballot -> uniform 64-bit mask in an SGPR pair, shifted per step.
//
// Numerics (r7/r9-proven, dead-beat): publish v' = q*u*e^{-GHAT} (f16, no
// feedback); barrier; z = q[0] of the consumed state (parity slot);
// q <- (E v')*rcp(z); Lam += GHAT + log z. Level = g_k - GHAT, bounded.

typedef _Float16 h2 __attribute__((ext_vector_type(2)));

#define B_  64
#define S_  1024
#define T_  128
#define PAD_IDX 0
#define EOS_IDX 3
#define BOT_IDX 1
#define GHAT         5.35f
#define EXP_NEG_GHAT 0.004736892f   // e^{-5.35}

#if defined(__has_builtin)
#if __has_builtin(__builtin_amdgcn_fdot2)
#define HAS_FDOT2 1
#endif
#endif

static __device__ __forceinline__ float dot2acc(unsigned eu, unsigned pu, float c) {
  h2 a = __builtin_bit_cast(h2, eu);
  h2 b = __builtin_bit_cast(h2, pu);
#ifdef HAS_FDOT2
  return __builtin_amdgcn_fdot2(a, b, c, false);
#else
  return fmaf((float)a.x, (float)b.x, fmaf((float)a.y, (float)b.y, c));
#endif
}

// x + (x from quad-permuted lane) via DPP; ctrl is an immediate (template)
template <int CTRL>
static __device__ __forceinline__ float dpp_add(float x) {
  int p = __builtin_amdgcn_update_dpp(0, __builtin_bit_cast(int, x),
                                      CTRL, 0xF, 0xF, true);
  return x + __builtin_bit_cast(float, p);
}

__global__ __launch_bounds__(256)
__attribute__((amdgpu_waves_per_eu(1, 1)))
void crf_logz_kernel(
    const int*   __restrict__ W,
    const float* __restrict__ emissions,
    const float* __restrict__ transitions,
    float*       __restrict__ out)
{
  const int b   = blockIdx.x;
  const int tid = threadIdx.x;
  const int l   = tid & 63;
  const int Q   = tid >> 2;          // quad id 0..63 -> rows 2Q, 2Q+1
  const int cp  = tid & 3;           // column quarter: cols [32cp, 32cp+32)
  const int rA  = 2 * Q;

  __shared__ __align__(16) unsigned vbuf[2][T_ / 2];  // packed half2 per quad
  __shared__ float zslot[2];
  __shared__ float fbuf[T_];

  // ---- E rows rA,rA+1, cols [32cp,+32) as 32 packed f16 pairs (32 VGPRs)
  unsigned Eu[32];   // [0..15] row A pairs, [16..31] row B pairs
  {
    const float2* ta = (const float2*)(transitions + (size_t)rA * T_ + 32 * cp);
    const float2* tb = (const float2*)(transitions + (size_t)(rA + 1) * T_ + 32 * cp);
    #pragma unroll
    for (int k = 0; k < 16; ++k) {
      float2 x = ta[k], y = tb[k];
      h2 ex, ey;
      ex.x = (_Float16)__expf(x.x); ex.y = (_Float16)__expf(x.y);
      ey.x = (_Float16)__expf(y.x); ey.y = (_Float16)__expf(y.y);
      Eu[k]      = __builtin_bit_cast(unsigned, ex);
      Eu[16 + k] = __builtin_bit_cast(unsigned, ey);
    }
  }

  if (tid == 0) { zslot[0] = 1.0f; zslot[1] = 1.0f; }
  __syncthreads();   // once, outside the hot loop

  const int*    Wrow = W + b * S_;
  const float2* emb2 = (const float2*)(emissions + (size_t)b * S_ * T_) + Q;

  float2 q;  q.x = 1.0f; q.y = 1.0f;   // exp-state rows rA, rA+1
  float  Lam = 0.0f;
  int    par = 0;

  // 4-deep em prefetch: slot0 holds consumed index i
  float2 e0 = emb2[(size_t)(S_ - 1) * 64];
  float2 e1 = emb2[(size_t)(S_ - 2) * 64];
  float2 e2 = emb2[(size_t)(S_ - 3) * 64];
  float2 e3 = emb2[(size_t)(S_ - 4) * 64];
  float2 us0, us1;
  us0.x = __expf(e0.x) * EXP_NEG_GHAT; us0.y = __expf(e0.y) * EXP_NEG_GHAT;
  us1.x = __expf(e1.x) * EXP_NEG_GHAT; us1.y = __expf(e1.y) * EXP_NEG_GHAT;

  for (int c = 15; c >= 0; --c) {
    // one vector load of 64 token ids -> uniform 64-bit activity mask (SGPRs)
    int wtok = Wrow[(c << 6) + l];
    unsigned long long m = __ballot((wtok != PAD_IDX) & (wtok != EOS_IDX));
    const int lo = (c == 0) ? 1 : 0;          // i==0 is never consumed

    for (int bit = 63; bit >= lo; --bit) {
      // keep E alive (zero instructions)
      asm volatile("" :: "v"(Eu[0]),  "v"(Eu[1]),  "v"(Eu[2]),  "v"(Eu[3]),
                         "v"(Eu[4]),  "v"(Eu[5]),  "v"(Eu[6]),  "v"(Eu[7]),
                         "v"(Eu[8]),  "v"(Eu[9]),  "v"(Eu[10]), "v"(Eu[11]),
                         "v"(Eu[12]), "v"(Eu[13]), "v"(Eu[14]), "v"(Eu[15]));
      asm volatile("" :: "v"(Eu[16]), "v"(Eu[17]), "v"(Eu[18]), "v"(Eu[19]),
                         "v"(Eu[20]), "v"(Eu[21]), "v"(Eu[22]), "v"(Eu[23]),
                         "v"(Eu[24]), "v"(Eu[25]), "v"(Eu[26]), "v"(Eu[27]),
                         "v"(Eu[28]), "v"(Eu[29]), "v"(Eu[30]), "v"(Eu[31]));

      const int i = (c << 6) + bit;           // consumed emission index
      int pf = i - 4; if (pf < 0) pf = 0;     // clamped tail re-read: harmless
      float2 en = emb2[(size_t)pf * 64];      // prefetch (vmcnt, not drained)

      const bool active = (long long)m < 0;   // top bit
      m <<= 1;

      if (active) {                           // block-uniform branch
        // publish v' = q .* us  (one lane per quad writes the packed pair)
        h2 vh; vh.x = (_Float16)(q.x * us0.x); vh.y = (_Float16)(q.y * us0.y);
        if (cp == 0) vbuf[par][Q] = __builtin_bit_cast(unsigned, vh);
        // drain own DS write, then barrier; NO vmcnt drain
        asm volatile("s_waitcnt lgkmcnt(0)\n\ts_barrier" ::: "memory");

        float z = zslot[par];
        const uint4* vb = ((const uint4*)&vbuf[par][0]) + (cp << 2);
        float aA0=0.f,aA1=0.f,aA2=0.f,aA3=0.f;
        float aB0=0.f,aB1=0.f,aB2=0.f,aB3=0.f;
        #pragma unroll
        for (int k = 0; k < 4; ++k) {
          uint4 pv = vb[k];                   // 4x ds_read_b128 per lane
          aA0 = dot2acc(Eu[4*k+0],      pv.x, aA0);
          aA1 = dot2acc(Eu[4*k+1],      pv.y, aA1);
          aA2 = dot2acc(Eu[4*k+2],      pv.z, aA2);
          aA3 = dot2acc(Eu[4*k+3],      pv.w, aA3);
          aB0 = dot2acc(Eu[16+4*k+0],   pv.x, aB0);
          aB1 = dot2acc(Eu[16+4*k+1],   pv.y, aB1);
          aB2 = dot2acc(Eu[16+4*k+2],   pv.z, aB2);
          aB3 = dot2acc(Eu[16+4*k+3],   pv.w, aB3);
        }
        float sA = (aA0 + aA1) + (aA2 + aA3);
        float sB = (aB0 + aB1) + (aB2 + aB3);
        // complete row sums across the quad: xor1 then xor2
        sA = dpp_add<0xB1>(sA); sA = dpp_add<0x4E>(sA);
        sB = dpp_add<0xB1>(sB); sB = dpp_add<0x4E>(sB);

        float rz = __builtin_amdgcn_rcpf(z);  // uniform
        q.x = sA * rz;
        q.y = sB * rz;
        if (tid == 0) zslot[par ^ 1] = q.x;   // row 0's value for NEXT step
        Lam += GHAT + __logf(z);              // exact compensation (off-path)
        par ^= 1;
      }
      // shift prefetch pipeline
      e0 = e1; us0 = us1;
      e1 = e2;
      e2 = e3;
      e3 = en;
      us1.x = __expf(e1.x) * EXP_NEG_GHAT;
      us1.y = __expf(e1.y) * EXP_NEG_GHAT;
    }
  }

  // ---- epilogue: f_r = trans[BOT,r] + em[b,0,r] + log q_r + Lam
  if (cp == 0) {
    float2 tb2 = *(const float2*)(transitions + BOT_IDX * T_ + rA);
    float2 f;
    f.x = tb2.x + e0.x + __logf(q.x);         // e0 ended as em[b,0,rA..rA+1]
    f.y = tb2.y + e0.y + __logf(q.y);
    *(float2*)&fbuf[rA] = f;
  }
  __syncthreads();
  if (tid < 64) {
    float x0 = fbuf[tid], x1 = fbuf[tid + 64];
    float m2 = fmaxf(x0, x1);
    #pragma unroll
    for (int off = 32; off; off >>= 1) m2 = fmaxf(m2, __shfl_xor(m2, off));
    float s = __expf(x0 - m2) + __expf(x1 - m2);
    #pragma unroll
    for (int off = 32; off; off >>= 1) s += __shfl_xor(s, off);
    if (tid == 0) out[b] = Lam + m2 + __logf(s);
  }
}

extern "C" void kernel_launch(void* const* d_in, const int* in_sizes, int n_in,
                              void* d_out, int out_size, void* d_ws, size_t ws_size,
                              hipStream_t stream) {
  const int*   W     = (const int*)d_in[0];
  const float* em    = (const float*)d_in[1];
  const float* trans = (const float*)d_in[2];
  float*       out   = (float*)d_out;
  (void)in_sizes; (void)n_in; (void)out_size; (void)d_ws; (void)ws_size;
  crf_logz_kernel<<<B_, 256, 0, stream>>>(W, em, trans, out);
}